// Round 7
// baseline (714.161 us; speedup 1.0000x reference)
//
#include <hip/hip_runtime.h>

#define NN 100000
#define EE 1600000
#define DIN 512
#define DH 256
#define DOUT 32
#define NSH 8

typedef _Float16 h16x8 __attribute__((ext_vector_type(8)));
typedef _Float16 h16x4 __attribute__((ext_vector_type(4)));
typedef float f32x4 __attribute__((ext_vector_type(4)));

union HU { unsigned int u; _Float16 h[2]; };

// ---------- weight transpose + fp16 convert ----------
__global__ __launch_bounds__(256) void conv_w1(const float* __restrict__ W1, _Float16* __restrict__ W1T){
  int i = blockIdx.x*256 + threadIdx.x;
  if (i < DIN*DH){
    int c = i >> 9, k = i & 511;          // W1T[c][k] = W1[k][c]
    W1T[i] = (_Float16)W1[k*DH + c];
  }
}
__global__ __launch_bounds__(256) void conv_w2(const float* __restrict__ W2, _Float16* __restrict__ W2T){
  int i = blockIdx.x*256 + threadIdx.x;
  if (i < DH*DOUT){
    int c = i >> 8, k = i & 255;          // W2T[c][k] = W2[k][c]
    W2T[i] = (_Float16)W2[k*DOUT + c];
  }
}

// ---------- GEMM1 (R3 124us engine, dedicated) ----------
__global__ __launch_bounds__(256) void gemm1(const float* __restrict__ feats,
    const _Float16* __restrict__ W1T, const float* __restrict__ b1,
    float* __restrict__ h1)
{
  const int gid  = blockIdx.x;
  const int col0 = (gid & 1) * 128;
  const int row0 = (gid >> 1) * 64;

  __shared__ _Float16 At[64][40];
  __shared__ _Float16 Bt[128][40];
  const int tid = threadIdx.x;
  const int lane = tid & 63, wave = tid >> 6;
  const int wr = wave >> 1, wc = wave & 1;
  const int l15 = lane & 15, kg = lane >> 4;
  const int arow = tid >> 2, aseg = (tid & 3) * 8;
  const int bcol = tid >> 1, bseg = (tid & 1) * 16;
  const bool aok = (row0 + arow) < NN;
  const float* aP = feats + (size_t)(row0+arow)*DIN + aseg;
  const _Float16* bP = W1T + (size_t)(col0+bcol)*DIN + bseg;

  f32x4 acc[2][4];
#pragma unroll
  for (int m=0;m<2;m++)
#pragma unroll
    for (int n=0;n<4;n++){ acc[m][n][0]=0.f; acc[m][n][1]=0.f; acc[m][n][2]=0.f; acc[m][n][3]=0.f; }

  float4 fa0 = make_float4(0,0,0,0), fa1 = make_float4(0,0,0,0);
  h16x8 fb0, fb1;
  if (aok){
    fa0 = *reinterpret_cast<const float4*>(aP);
    fa1 = *reinterpret_cast<const float4*>(aP + 4);
  }
  fb0 = *reinterpret_cast<const h16x8*>(bP);
  fb1 = *reinterpret_cast<const h16x8*>(bP + 8);

  for (int t=0; t<16; ++t){
    {
      h16x4 v0, v1;
      v0[0]=(_Float16)fa0.x; v0[1]=(_Float16)fa0.y; v0[2]=(_Float16)fa0.z; v0[3]=(_Float16)fa0.w;
      v1[0]=(_Float16)fa1.x; v1[1]=(_Float16)fa1.y; v1[2]=(_Float16)fa1.z; v1[3]=(_Float16)fa1.w;
      *reinterpret_cast<h16x4*>(&At[arow][aseg])   = v0;
      *reinterpret_cast<h16x4*>(&At[arow][aseg+4]) = v1;
      *reinterpret_cast<h16x8*>(&Bt[bcol][bseg])   = fb0;
      *reinterpret_cast<h16x8*>(&Bt[bcol][bseg+8]) = fb1;
    }
    __syncthreads();
    if (t < 15){
      int k0 = (t+1)*32;
      if (aok){
        fa0 = *reinterpret_cast<const float4*>(aP + k0);
        fa1 = *reinterpret_cast<const float4*>(aP + k0 + 4);
      }
      fb0 = *reinterpret_cast<const h16x8*>(bP + k0);
      fb1 = *reinterpret_cast<const h16x8*>(bP + k0 + 8);
    }
    h16x8 af[2], bfr[4];
#pragma unroll
    for (int m=0;m<2;m++) af[m]  = *reinterpret_cast<const h16x8*>(&At[wr*32 + m*16 + l15][kg*8]);
#pragma unroll
    for (int n=0;n<4;n++) bfr[n] = *reinterpret_cast<const h16x8*>(&Bt[wc*64 + n*16 + l15][kg*8]);
#pragma unroll
    for (int m=0;m<2;m++)
#pragma unroll
      for (int n=0;n<4;n++)
        acc[m][n] = __builtin_amdgcn_mfma_f32_16x16x32_f16(af[m], bfr[n], acc[m][n], 0, 0, 0);
    __syncthreads();
  }
  const int rb = kg*4;
#pragma unroll
  for (int n=0;n<4;n++){
    int col = col0 + wc*64 + n*16 + l15;
    float bias = b1[col];
#pragma unroll
    for (int m=0;m<2;m++){
#pragma unroll
      for (int j=0;j<4;j++){
        int g = row0 + wr*32 + m*16 + rb + j;
        if (g < NN) h1[(size_t)g*DH + col] = acc[m][n][j] + bias;
      }
    }
  }
}

// ---------- XCD-sharded degree + rank (atomics stay in local L2) ----------
__global__ __launch_bounds__(256) void deg_shard(
    const int* __restrict__ src, const int* __restrict__ dst,
    int* __restrict__ degO_sh, int* __restrict__ degI_sh, int* __restrict__ rnk)
{
  const int b = blockIdx.x;                    // 6250 blocks, EE = 6250*256 exactly
  const int i = b*256 + threadIdx.x;
  const int sh = b & (NSH-1);
  int s = src[i], d = dst[i];
  atomicAdd(&degO_sh[(size_t)sh*NN + s], 1);
  rnk[i] = atomicAdd(&degI_sh[(size_t)sh*NN + d], 1);
}

// ---------- combine shards -> degI, nS, nD; degI_sh becomes per-shard base ----------
__global__ __launch_bounds__(256) void combine(
    const int* __restrict__ degO_sh, int* __restrict__ degI_sh,
    int* __restrict__ degI, float* __restrict__ nS, float* __restrict__ nD)
{
  int v = blockIdx.x*256 + threadIdx.x;
  if (v >= NN) return;
  int so = 0, si = 0;
  int b[NSH];
#pragma unroll
  for (int x=0;x<NSH;x++) so += degO_sh[(size_t)x*NN + v];
#pragma unroll
  for (int x=0;x<NSH;x++){ b[x] = si; si += degI_sh[(size_t)x*NN + v]; }
#pragma unroll
  for (int x=0;x<NSH;x++) degI_sh[(size_t)x*NN + v] = b[x];
  degI[v] = si;
  nS[v] = rsqrtf((float)(so > 0 ? so : 1));
  nD[v] = rsqrtf((float)(si > 0 ? si : 1));
}

// ---------- scans (offs = exclusive prefix of degI) ----------
__global__ __launch_bounds__(1024) void scan1(const int* __restrict__ degI, int* __restrict__ offs, int* __restrict__ bsum){
  __shared__ int sm[1024];
  int t = threadIdx.x;
  int g = blockIdx.x*1024 + t;
  int v = (g < NN) ? degI[g] : 0;
  sm[t] = v; __syncthreads();
  for (int o=1;o<1024;o<<=1){
    int a = (t>=o)? sm[t-o] : 0;
    __syncthreads();
    sm[t] += a;
    __syncthreads();
  }
  if (g < NN) offs[g] = sm[t] - v;
  if (t == 1023) bsum[blockIdx.x] = sm[t];
}
__global__ __launch_bounds__(128) void scan2(const int* __restrict__ bsum, int* __restrict__ boff, int nb){
  __shared__ int sm[128];
  int t = threadIdx.x;
  int v = (t < nb)? bsum[t] : 0;
  sm[t] = v; __syncthreads();
  for (int o=1;o<128;o<<=1){
    int a = (t>=o)? sm[t-o] : 0;
    __syncthreads();
    sm[t] += a;
    __syncthreads();
  }
  if (t < nb) boff[t] = sm[t] - v;
}
__global__ __launch_bounds__(256) void scan3(int* __restrict__ offs, const int* __restrict__ boff){
  int i = blockIdx.x*256 + threadIdx.x;
  if (i < NN) offs[i] += boff[i >> 10];
}
// fold offs into per-shard bases: degI_sh[x][v] += offs[v]
__global__ __launch_bounds__(256) void addoffs(int* __restrict__ degI_sh, const int* __restrict__ offs){
  int v = blockIdx.x*256 + threadIdx.x;
  if (v < NN){
    int o = offs[v];
#pragma unroll
    for (int x=0;x<NSH;x++) degI_sh[(size_t)x*NN + v] += o;
  }
}

// ---------- fused2: LDS-free GEMM2 + atomic-free CSR scatter ----------
__global__ __launch_bounds__(256) void fused2(
    const float* __restrict__ h1, const _Float16* __restrict__ W2T,
    const float* __restrict__ b2, const float* __restrict__ nS,
    _Float16* __restrict__ h0h, _Float16* __restrict__ hsh,
    const int* __restrict__ src, const int* __restrict__ dst,
    const int* __restrict__ base_sh, const int* __restrict__ rnk,
    int* __restrict__ csrc)
{
  const int bid = blockIdx.x;
  const int tid = threadIdx.x;
  if (bid < 1024){
    for (int i = bid*256 + tid; i < EE; i += 1024*256){
      int sh = (i >> 8) & (NSH-1);
      csrc[base_sh[(size_t)sh*NN + dst[i]] + rnk[i]] = src[i];
    }
    return;
  }
  const int gid = bid - 1024;
  const int row0 = gid * 256;
  const int lane = tid & 63, wave = tid >> 6;
  const int l15 = lane & 15, kg = lane >> 4;

  f32x4 acc[4][2];
#pragma unroll
  for (int m=0;m<4;m++)
#pragma unroll
    for (int n=0;n<2;n++){ acc[m][n][0]=0.f; acc[m][n][1]=0.f; acc[m][n][2]=0.f; acc[m][n][3]=0.f; }

  const float* aP[4]; bool aok[4];
#pragma unroll
  for (int m=0;m<4;m++){
    int r = row0 + wave*64 + m*16 + l15;
    aok[m] = (r < NN);
    aP[m] = h1 + (size_t)r*DH + kg*8;
  }
  const _Float16* bP[2];
#pragma unroll
  for (int n=0;n<2;n++)
    bP[n] = W2T + (size_t)(n*16 + l15)*DH + kg*8;

  for (int t=0; t<8; ++t){
    const int k0 = t*32;
    h16x8 bf[2], af[4];
#pragma unroll
    for (int n=0;n<2;n++) bf[n] = *reinterpret_cast<const h16x8*>(bP[n] + k0);
#pragma unroll
    for (int m=0;m<4;m++){
      float4 x = make_float4(0,0,0,0), y = make_float4(0,0,0,0);
      if (aok[m]){
        x = *reinterpret_cast<const float4*>(aP[m] + k0);
        y = *reinterpret_cast<const float4*>(aP[m] + k0 + 4);
      }
      h16x8 v;
      v[0]=(_Float16)fmaxf(x.x,0.f); v[1]=(_Float16)fmaxf(x.y,0.f);
      v[2]=(_Float16)fmaxf(x.z,0.f); v[3]=(_Float16)fmaxf(x.w,0.f);
      v[4]=(_Float16)fmaxf(y.x,0.f); v[5]=(_Float16)fmaxf(y.y,0.f);
      v[6]=(_Float16)fmaxf(y.z,0.f); v[7]=(_Float16)fmaxf(y.w,0.f);
      af[m] = v;
    }
#pragma unroll
    for (int m=0;m<4;m++)
#pragma unroll
      for (int n=0;n<2;n++)
        acc[m][n] = __builtin_amdgcn_mfma_f32_16x16x32_f16(af[m], bf[n], acc[m][n], 0, 0, 0);
  }
  const int rb = kg*4;
#pragma unroll
  for (int n=0;n<2;n++){
    int col = n*16 + l15;
    float bias = b2[col];
#pragma unroll
    for (int m=0;m<4;m++){
#pragma unroll
      for (int j=0;j<4;j++){
        int g = row0 + wave*64 + m*16 + rb + j;
        if (g < NN){
          float val = acc[m][n][j] + bias;
          h0h[(size_t)g*DOUT + col] = (_Float16)val;
          hsh[(size_t)g*DOUT + col] = (_Float16)(nS[g] * val);
        }
      }
    }
  }
}

// ---------- APPNP prop: grid-stride waves, 2 independent nodes per iteration ----------
template<bool LAST>
__global__ __launch_bounds__(256) void prop(
    const unsigned int* __restrict__ hs,   // nS-scaled fp16 rows [NN][16]
    const unsigned int* __restrict__ h0,   // unscaled fp16 rows [NN][16]
    unsigned int* __restrict__ hs_out,
    float2* __restrict__ out2,
    const int* __restrict__ offs, const int* __restrict__ degI,
    const int* __restrict__ csrc,
    const float* __restrict__ nS, const float* __restrict__ nD)
{
  const int nw = gridDim.x * 4;
  int wid = (blockIdx.x*256 + threadIdx.x) >> 6;
  const int lane = threadIdx.x & 63;
  const int slot = lane >> 4;      // 4 edge slots
  const int c    = lane & 15;      // uint index within 64B row

  for (int v0 = wid; v0 < NN; v0 += 2*nw){
    const int v1 = v0 + nw;
    const bool has1 = (v1 < NN);
    int beg0 = offs[v0], cnt0 = degI[v0];
    int beg1 = 0, cnt1 = 0;
    if (has1){ beg1 = offs[v1]; cnt1 = degI[v1]; }
    float ax=0.f, ay=0.f, bx=0.f, by=0.f;
    int i0 = slot, i1 = slot;
    while (i0 + 4 < cnt0 && i1 + 4 < cnt1){
      int sA0 = csrc[beg0+i0], sA1 = csrc[beg0+i0+4];
      int sB0 = csrc[beg1+i1], sB1 = csrc[beg1+i1+4];
      HU uA0, uA1, uB0, uB1;
      uA0.u = hs[(size_t)sA0*16 + c];
      uA1.u = hs[(size_t)sA1*16 + c];
      uB0.u = hs[(size_t)sB0*16 + c];
      uB1.u = hs[(size_t)sB1*16 + c];
      ax += (float)uA0.h[0] + (float)uA1.h[0];
      ay += (float)uA0.h[1] + (float)uA1.h[1];
      bx += (float)uB0.h[0] + (float)uB1.h[0];
      by += (float)uB0.h[1] + (float)uB1.h[1];
      i0 += 8; i1 += 8;
    }
    for (; i0 < cnt0; i0 += 4){
      HU u; u.u = hs[(size_t)csrc[beg0+i0]*16 + c];
      ax += (float)u.h[0]; ay += (float)u.h[1];
    }
    for (; i1 < cnt1; i1 += 4){
      HU u; u.u = hs[(size_t)csrc[beg1+i1]*16 + c];
      bx += (float)u.h[0]; by += (float)u.h[1];
    }
    ax += __shfl_xor(ax,16); ay += __shfl_xor(ay,16);
    ax += __shfl_xor(ax,32); ay += __shfl_xor(ay,32);
    bx += __shfl_xor(bx,16); by += __shfl_xor(by,16);
    bx += __shfl_xor(bx,32); by += __shfl_xor(by,32);
    if (slot == 0){
      {
        float nd = nD[v0];
        HU hp; hp.u = h0[(size_t)v0*16 + c];
        float rx = 0.9f*nd*ax + 0.1f*(float)hp.h[0];
        float ry = 0.9f*nd*ay + 0.1f*(float)hp.h[1];
        if (LAST){
          out2[(size_t)v0*16 + c] = make_float2(rx, ry);
        } else {
          float ns = nS[v0];
          HU o; o.h[0] = (_Float16)(ns*rx); o.h[1] = (_Float16)(ns*ry);
          hs_out[(size_t)v0*16 + c] = o.u;
        }
      }
      if (has1){
        float nd = nD[v1];
        HU hp; hp.u = h0[(size_t)v1*16 + c];
        float rx = 0.9f*nd*bx + 0.1f*(float)hp.h[0];
        float ry = 0.9f*nd*by + 0.1f*(float)hp.h[1];
        if (LAST){
          out2[(size_t)v1*16 + c] = make_float2(rx, ry);
        } else {
          float ns = nS[v1];
          HU o; o.h[0] = (_Float16)(ns*rx); o.h[1] = (_Float16)(ns*ry);
          hs_out[(size_t)v1*16 + c] = o.u;
        }
      }
    }
  }
}

extern "C" void kernel_launch(void* const* d_in, const int* in_sizes, int n_in,
                              void* d_out, int out_size, void* d_ws, size_t ws_size,
                              hipStream_t stream)
{
  const float* feats = (const float*)d_in[0];
  const int*   src   = (const int*)d_in[1];
  const int*   dst   = (const int*)d_in[2];
  const float* W1    = (const float*)d_in[3];
  const float* b1    = (const float*)d_in[4];
  const float* W2    = (const float*)d_in[5];
  const float* b2    = (const float*)d_in[6];
  float* out = (float*)d_out;

  char* ws = (char*)d_ws;
  size_t off = 0;
  auto alloc = [&](size_t bytes) -> void* {
    void* p = ws + off;
    off = (off + bytes + 255) & ~(size_t)255;
    return p;
  };
  _Float16* W1T = (_Float16*)alloc((size_t)DIN*DH*2);
  _Float16* W2T = (_Float16*)alloc((size_t)DH*DOUT*2);
  int* degO_sh  = (int*)  alloc((size_t)NSH*NN*4);
  int* degI_sh  = (int*)  alloc((size_t)NSH*NN*4);
  int*   degI   = (int*)  alloc((size_t)NN*4);
  float* nS     = (float*)alloc((size_t)NN*4);
  float* nD     = (float*)alloc((size_t)NN*4);
  int*   offs   = (int*)  alloc((size_t)NN*4);
  int*   bsum   = (int*)  alloc(512);
  int*   boff   = (int*)  alloc(512);
  int*   rnk    = (int*)  alloc((size_t)EE*4);
  int*   csrc   = (int*)  alloc((size_t)EE*4);
  _Float16* h0h = (_Float16*)alloc((size_t)NN*DOUT*2);
  _Float16* hs0 = (_Float16*)alloc((size_t)NN*DOUT*2);
  unsigned int* pA = (unsigned int*)alloc((size_t)NN*DOUT*2);
  unsigned int* pB = (unsigned int*)alloc((size_t)NN*DOUT*2);

  hipMemsetAsync(degO_sh, 0, (size_t)NSH*NN*4, stream);
  hipMemsetAsync(degI_sh, 0, (size_t)NSH*NN*4, stream);

  conv_w1<<<(DIN*DH+255)/256, 256, 0, stream>>>(W1, W1T);
  conv_w2<<<(DH*DOUT+255)/256, 256, 0, stream>>>(W2, W2T);

  deg_shard<<<EE/256, 256, 0, stream>>>(src, dst, degO_sh, degI_sh, rnk);
  combine<<<(NN+255)/256, 256, 0, stream>>>(degO_sh, degI_sh, degI, nS, nD);

  gemm1<<<2*((NN+63)/64), 256, 0, stream>>>(feats, W1T, b1, out);

  int nb = (NN+1023)/1024;
  scan1<<<nb, 1024, 0, stream>>>(degI, offs, bsum);
  scan2<<<1, 128, 0, stream>>>(bsum, boff, nb);
  scan3<<<(NN+255)/256, 256, 0, stream>>>(offs, boff);
  addoffs<<<(NN+255)/256, 256, 0, stream>>>(degI_sh, offs);

  fused2<<<1024 + (NN+255)/256, 256, 0, stream>>>(out, W2T, b2, nS, h0h, hs0,
                                                  src, dst, degI_sh, rnk, csrc);

  float2* out2 = (float2*)(out + (size_t)NN*DH);
  const unsigned int* cur = (const unsigned int*)hs0;
  const unsigned int* h0u = (const unsigned int*)h0h;
  for (int it=0; it<9; ++it){
    unsigned int* nxt = (it&1)? pB : pA;
    prop<false><<<2048, 256, 0, stream>>>(cur, h0u, nxt, nullptr, offs, degI, csrc, nS, nD);
    cur = nxt;
  }
  prop<true><<<2048, 256, 0, stream>>>(cur, h0u, nullptr, out2, offs, degI, csrc, nS, nD);
}